// Round 8
// baseline (119.863 us; speedup 1.0000x reference)
//
#include <hip/hip_runtime.h>
#include <math.h>
#include <stdint.h>

typedef short bf16x8 __attribute__((ext_vector_type(8)));   // 8 bf16 (4 VGPRs)
typedef float f32x4 __attribute__((ext_vector_type(4)));

#define NFRAGS 36
#define T 6                 // point-tiles (16 pts) per wave — 6 independent chains
#define NW 4                // waves per block
#define BS 256
#define PTS_BLK (NW * T * 16)   // 384 points per block

// RNE float -> bf16 bits (prologue only; weights keep full rounding quality)
__device__ __forceinline__ uint32_t f2bf_rne(float f) {
    uint32_t u = __float_as_uint(f);
    return (u + 0x7FFFu + ((u >> 16) & 1u)) >> 16;
}

// ---- hot-path pack: TRUNCATING f32x2 -> packed bf16 in ONE v_perm ----
__device__ __forceinline__ uint32_t pk2(float a, float b) {
    return __builtin_amdgcn_perm(__float_as_uint(b), __float_as_uint(a), 0x07060302u);
}
// relu on packed bf16 pair (bf16 bits as i16: negative iff float negative)
__device__ __forceinline__ uint32_t relu2(uint32_t x) {
    uint32_t r;
    asm("v_pk_max_i16 %0, %1, 0" : "=v"(r) : "v"(x));
    return r;
}
__device__ __forceinline__ uint32_t pk2r(float a, float b) { return relu2(pk2(a, b)); }
__device__ __forceinline__ uint16_t bfu(float v) { return (uint16_t)(__float_as_uint(v) >> 16); }

// producer storage permutation: f = sperm(s), swap bits [5:4] <-> [3:2]
__device__ __forceinline__ int sperm(int k) {
    return (k & 3) | (((k >> 2) & 3) << 4) | (((k >> 4) & 3) << 2);
}
// register-transpose permutation: hw-k -> storage-s after 4x permlane32_swap
// s = {k5, k3, k4, k2, k1, k0}
__device__ __forceinline__ int rperm(int k) {
    return (k & 32) | (((k >> 3) & 1) << 4) | (((k >> 4) & 1) << 3) | (k & 7);
}

// ---------------- prologue: pack 36 A-fragments into d_ws ----------------
// pm=0: plain k (LDS-fed layers: ws0, wc0). pm=2: register-transpose-fed
// layers (ws1, ws2, wc1, wc2, wc3): weight at hw-k = W[sperm(rperm(k))].
__global__ void pack_weights(const float* __restrict__ ws0, const float* __restrict__ ws1,
                             const float* __restrict__ ws2, const float* __restrict__ wc0,
                             const float* __restrict__ wc1, const float* __restrict__ wc2,
                             const float* __restrict__ wc3, uint4* __restrict__ wpack) {
    int idx = blockIdx.x * blockDim.x + threadIdx.x;
    if (idx >= NFRAGS * 64) return;
    int F = idx >> 6, cl = idx & 63, cm = cl & 15, cq = cl >> 4;
    const float* w; int IN, OUT, mt, ks, pm;
    if (F < 4)       { w = ws0; IN = 3;  OUT = 64; mt = F;            ks = 0;          pm = 0; }
    else if (F < 12) { w = ws1; IN = 64; OUT = 64; mt = (F-4) >> 1;   ks = (F-4) & 1;  pm = 2; }
    else if (F < 14) { w = ws2; IN = 64; OUT = 16; mt = 0;            ks = F - 12;     pm = 2; }
    else if (F < 18) { w = wc0; IN = 18; OUT = 64; mt = F - 14;       ks = 0;          pm = 0; }
    else if (F < 26) { w = wc1; IN = 64; OUT = 64; mt = (F-18) >> 1;  ks = (F-18) & 1; pm = 2; }
    else if (F < 34) { w = wc2; IN = 64; OUT = 64; mt = (F-26) >> 1;  ks = (F-26) & 1; pm = 2; }
    else             { w = wc3; IN = 64; OUT = 3;  mt = 0;            ks = F - 34;     pm = 2; }
    const int fo = mt * 16 + cm;
    uint32_t pk[4];
    for (int jj = 0; jj < 4; ++jj) {
        uint32_t h[2];
        for (int bb = 0; bb < 2; ++bb) {
            int kg = ks * 32 + cq * 8 + jj * 2 + bb;      // hw k position
            int kr = (pm == 2) ? sperm(rperm(kg)) : kg;   // source feature index
            float v = 0.f;
            if (fo < OUT && kr < IN) v = w[kr * OUT + fo];
            h[bb] = f2bf_rne(v);
        }
        pk[jj] = h[0] | (h[1] << 16);
    }
    wpack[F * 64 + cl] = make_uint4(pk[0], pk[1], pk[2], pk[3]);
}

// ---------------- main kernel ----------------
// R8 = R5 structure (4-wave blocks, per-tile layer bodies, setprio on MFMA
// clusters, paired-tile 1KB/tile LDS) + T=6: all per-wave fixed costs
// (36 weight-fragment loads ~1400cy stall + ~150 VALU addressing, staging
// prologue, epilogue) amortize over 96 points instead of 64, and total
// waves drop 16384->10924. Quadrant q stages tile q; quadrants 0,1 also
// stage tiles 4,5 (views kept in vvb). Keeps R6's bit-identical cuts
// (granule-0-only staging, masked L0/L3 reads, granule-2-only zeroing).
// HISTORY (do not revisit):
//  * pair-interleaved MFMA bursts (R6): REGRESSED — compiler re-serialized
//    (VGPR collapsed to 56), every dispatch >=44.2 µs.
//  * NW=8 512-thread blocks (R7): REGRESSED 47.5 µs; occupancy unchanged —
//    dispatch churn is NOT the limiter.
//  * LDS-weights + persistent blocks (R3): REGRESSED 51.5 µs.
//  * launch_bounds(,8): 32-reg cap -> 1.2 GB scratch spill, 7x regression.
__global__ __launch_bounds__(BS, 4) void nerf_main(const float* __restrict__ xin,
                                                   const uint4* __restrict__ wpack,
                                                   float* __restrict__ outp, int n) {
    __shared__ __align__(16) char smem[NW * T * 1024];   // 24 KB
    const int tid = threadIdx.x, wv = tid >> 6, lane = tid & 63;
    const int p = lane & 15, q = lane >> 4;
    const int sw = p & 7;
    char* actw = smem + wv * (T * 1024);
    const int base = blockIdx.x * PTS_BLK + wv * (T * 16);

    // paired-tile swizzled address: tile t granule g (g in 0..3)
    auto aaddr = [&](int t, int g) -> char* {
        return actw + (t >> 1) * 2048 + p * 128 + (((g ^ ((t & 1) << 2)) ^ sw) << 4);
    };
    auto ldA = [&](int F) -> bf16x8 {
        uint4 u = wpack[F * 64 + lane];
        return *(bf16x8*)&u;
    };
    const f32x4 z4 = {0.f, 0.f, 0.f, 0.f};

    // D (4 m-tiles) -> pack+relu -> 4x v_permlane32_swap -> next layer's B frags.
    auto xpose = [&](const f32x4* d, bf16x8& b0, bf16x8& b1) {
        uint32_t X0 = pk2r(d[0][0], d[0][1]), X1 = pk2r(d[0][2], d[0][3]);
        uint32_t X2 = pk2r(d[1][0], d[1][1]), X3 = pk2r(d[1][2], d[1][3]);
        uint32_t X4 = pk2r(d[2][0], d[2][1]), X5 = pk2r(d[2][2], d[2][3]);
        uint32_t X6 = pk2r(d[3][0], d[3][1]), X7 = pk2r(d[3][2], d[3][3]);
        asm("v_permlane32_swap_b32 %0, %1" : "+v"(X0), "+v"(X4));
        asm("v_permlane32_swap_b32 %0, %1" : "+v"(X1), "+v"(X5));
        asm("v_permlane32_swap_b32 %0, %1" : "+v"(X2), "+v"(X6));
        asm("v_permlane32_swap_b32 %0, %1" : "+v"(X3), "+v"(X7));
        uint4 u0 = make_uint4(X0, X1, X2, X3), u1 = make_uint4(X4, X5, X6, X7);
        b0 = *(bf16x8*)&u0; b1 = *(bf16x8*)&u1;
    };

    // ---- staging: quadrant q stages tile q (point base+q*16+p); quadrants
    // 0,1 additionally stage tiles 4,5. ONLY granule 0 written (k=0..7 =
    // x0,x1,x2,0,...); q>0 B-frags in L0 are register zeros (masked read).
    float vva0 = 0.f, vva1 = 0.f, vva2 = 0.f;   // views for tile q
    float vvb0 = 0.f, vvb1 = 0.f, vvb2 = 0.f;   // views for tile 4+q (q<2)
    {
        float x0 = 0.f, x1 = 0.f, x2 = 0.f;
        const int pi = base + q * 16 + p;
        if (pi < n) {
            const float2* xp = (const float2*)(xin + (size_t)pi * 6);
            float2 a = xp[0], b = xp[1], c = xp[2];
            x0 = a.x; x1 = a.y; x2 = b.x; vva0 = b.y; vva1 = c.x; vva2 = c.y;
        }
        *(uint4*)aaddr(q, 0) = make_uint4(pk2(x0, x1), pk2(x2, 0.f), 0u, 0u);
        if (q < 2) {
            float y0 = 0.f, y1 = 0.f, y2 = 0.f;
            const int pj = base + (4 + q) * 16 + p;
            if (pj < n) {
                const float2* yp = (const float2*)(xin + (size_t)pj * 6);
                float2 a = yp[0], b = yp[1], c = yp[2];
                y0 = a.x; y1 = a.y; y2 = b.x; vvb0 = b.y; vvb1 = c.x; vvb2 = c.y;
            }
            *(uint4*)aaddr(4 + q, 0) = make_uint4(pk2(y0, y1), pk2(y2, 0.f), 0u, 0u);
        }
    }

    bf16x8 c0[T], c1[T];   // live activation fragments (register path)

    // K=32 LDS-fed layer (L0: ws0 qmax=1, L3: wc0 qmax=3) — per-tile xpose
    auto layerK32 = [&](int FB, int qmax) {
        bf16x8 W0 = ldA(FB), W1 = ldA(FB + 1), W2 = ldA(FB + 2), W3 = ldA(FB + 3);
#pragma unroll
        for (int t = 0; t < T; ++t) {
            bf16x8 b = 0;
            if (q < qmax) b = *(const bf16x8*)aaddr(t, q);
            f32x4 d[4];
            d[0] = __builtin_amdgcn_mfma_f32_16x16x32_bf16(W0, b, z4, 0, 0, 0);
            d[1] = __builtin_amdgcn_mfma_f32_16x16x32_bf16(W1, b, z4, 0, 0, 0);
            d[2] = __builtin_amdgcn_mfma_f32_16x16x32_bf16(W2, b, z4, 0, 0, 0);
            d[3] = __builtin_amdgcn_mfma_f32_16x16x32_bf16(W3, b, z4, 0, 0, 0);
            xpose(d, c0[t], c1[t]);
        }
    };

    // 64->64 register-fed layer — per-tile xpose, MFMA cluster under setprio
    auto layer64 = [&](int FB) {
        bf16x8 W[8];
#pragma unroll
        for (int i = 0; i < 8; ++i) W[i] = ldA(FB + i);
#pragma unroll
        for (int t = 0; t < T; ++t) {
            f32x4 d[4];
            __builtin_amdgcn_s_setprio(1);
#pragma unroll
            for (int mt = 0; mt < 4; ++mt) {
                f32x4 acc = __builtin_amdgcn_mfma_f32_16x16x32_bf16(W[mt*2],   c0[t], z4,  0, 0, 0);
                d[mt]     = __builtin_amdgcn_mfma_f32_16x16x32_bf16(W[mt*2+1], c1[t], acc, 0, 0, 0);
            }
            __builtin_amdgcn_s_setprio(0);
            xpose(d, c0[t], c1[t]);
        }
    };

    // ---- L0: sigma net 3->64 (frags 0..3), LDS-fed (q==0 only) ----
    layerK32(0, 1);

    // ---- L1: sigma net 64->64 (frags 4..11) ----
    layer64(4);

    // ---- L2: ws2 64->16 (frags 12,13): sigma + color-input assembly (LDS) ----
    float sig[T];
    {
        bf16x8 A0 = ldA(12), A1 = ldA(13);
#pragma unroll
        for (int t = 0; t < T; ++t) {
            f32x4 acc = __builtin_amdgcn_mfma_f32_16x16x32_bf16(A0, c0[t], z4,  0, 0, 0);
            f32x4 d   = __builtin_amdgcn_mfma_f32_16x16x32_bf16(A1, c1[t], acc, 0, 0, 0);
            const float sx = d[0];                       // feat0 valid on q==0 lanes
            sig[t] = fmaxf(sx, 0.f) + __logf(1.f + __expf(-fabsf(sx)));
            // granules 0/1 are fully overwritten by the scatter below; only
            // granule 2 needs zeroing (k=18..23 dead inputs); granule 3 dead.
            if (q == 2) *(uint4*)aaddr(t, 2) = make_uint4(0u, 0u, 0u, 0u);
            // views of point p, tile t: t<4 on lane (p,t) [vva]; t>=4 on
            // lane (p,t-4) [vvb].
            if (t < 4) {
                if (q == t) {
                    *(uint32_t*)(aaddr(t, 0) + 0) = pk2(vva0, vva1);
                    *(uint16_t*)(aaddr(t, 0) + 4) = bfu(vva2);
                }
            } else {
                if (q == t - 4) {
                    *(uint32_t*)(aaddr(t, 0) + 0) = pk2(vvb0, vvb1);
                    *(uint16_t*)(aaddr(t, 0) + 4) = bfu(vvb2);
                }
            }
            // geo feats f=4q+r (f>=1) -> color k=f+2
            if (q == 0) {
                *(uint16_t*)(aaddr(t, 0) + 6) = bfu(d[1]);
                *(uint32_t*)(aaddr(t, 0) + 8) = pk2(d[2], d[3]);
            } else if (q == 1) {
                *(uint32_t*)(aaddr(t, 0) + 12) = pk2(d[0], d[1]);
                *(uint32_t*)(aaddr(t, 1) + 0)  = pk2(d[2], d[3]);
            } else if (q == 2) {
                *(uint32_t*)(aaddr(t, 1) + 4) = pk2(d[0], d[1]);
                *(uint32_t*)(aaddr(t, 1) + 8) = pk2(d[2], d[3]);
            } else {
                *(uint32_t*)(aaddr(t, 1) + 12) = pk2(d[0], d[1]);
                *(uint32_t*)(aaddr(t, 2) + 0)  = pk2(d[2], d[3]);
            }
        }
    }

    // ---- L3: wc0 18->64 (frags 14..17), LDS-fed (q<3; granule 3 is dead) ----
    layerK32(14, 3);

    // ---- L4, L5: wc1, wc2 64->64 ----
    layer64(18);
    layer64(26);

    // ---- L6: wc3 64->3 (frags 34,35) + output ----
    {
        bf16x8 A0 = ldA(34), A1 = ldA(35);
#pragma unroll
        for (int t = 0; t < T; ++t) {
            f32x4 acc = __builtin_amdgcn_mfma_f32_16x16x32_bf16(A0, c0[t], z4,  0, 0, 0);
            f32x4 d   = __builtin_amdgcn_mfma_f32_16x16x32_bf16(A1, c1[t], acc, 0, 0, 0);
            if (q == 0) {
                const int pt = base + t * 16 + p;
                if (pt < n)
                    *(float4*)(outp + (size_t)pt * 4) = make_float4(d[0], d[1], d[2], sig[t]);
            }
        }
    }
}

extern "C" void kernel_launch(void* const* d_in, const int* in_sizes, int n_in,
                              void* d_out, int out_size, void* d_ws, size_t ws_size,
                              hipStream_t stream) {
    const float* x   = (const float*)d_in[0];
    const float* ws0 = (const float*)d_in[1];
    const float* ws1 = (const float*)d_in[2];
    const float* ws2 = (const float*)d_in[3];
    const float* wc0 = (const float*)d_in[4];
    const float* wc1 = (const float*)d_in[5];
    const float* wc2 = (const float*)d_in[6];
    const float* wc3 = (const float*)d_in[7];
    float* out = (float*)d_out;
    uint4* wpack = (uint4*)d_ws;

    const int n = in_sizes[0] / 6;
    pack_weights<<<(NFRAGS * 64 + 255) / 256, 256, 0, stream>>>(ws0, ws1, ws2, wc0, wc1, wc2, wc3, wpack);
    const int grid = (n + PTS_BLK - 1) / PTS_BLK;
    nerf_main<<<grid, BS, 0, stream>>>(x, wpack, out, n);
}

// Round 9
// 115.319 us; speedup vs baseline: 1.0394x; 1.0394x over previous
//
#include <hip/hip_runtime.h>
#include <math.h>
#include <stdint.h>

typedef short bf16x8 __attribute__((ext_vector_type(8)));   // 8 bf16 (4 VGPRs)
typedef float f32x4 __attribute__((ext_vector_type(4)));

#define NFRAGS 36
#define T 4                 // point-tiles (16 pts) per wave
#define NW 4                // waves per block
#define BS 256
#define PTS_BLK (NW * T * 16)   // 256 points per block

// RNE float -> bf16 bits (prologue only; weights keep full rounding quality)
__device__ __forceinline__ uint32_t f2bf_rne(float f) {
    uint32_t u = __float_as_uint(f);
    return (u + 0x7FFFu + ((u >> 16) & 1u)) >> 16;
}

// ---- hot-path pack: TRUNCATING f32x2 -> packed bf16 in ONE v_perm ----
__device__ __forceinline__ uint32_t pk2(float a, float b) {
    return __builtin_amdgcn_perm(__float_as_uint(b), __float_as_uint(a), 0x07060302u);
}
// relu on packed bf16 pair (bf16 bits as i16: negative iff float negative)
__device__ __forceinline__ uint32_t relu2(uint32_t x) {
    uint32_t r;
    asm("v_pk_max_i16 %0, %1, 0" : "=v"(r) : "v"(x));
    return r;
}
__device__ __forceinline__ uint32_t pk2r(float a, float b) { return relu2(pk2(a, b)); }
__device__ __forceinline__ uint16_t bfu(float v) { return (uint16_t)(__float_as_uint(v) >> 16); }

// producer storage permutation: f = sperm(s), swap bits [5:4] <-> [3:2]
__device__ __forceinline__ int sperm(int k) {
    return (k & 3) | (((k >> 2) & 3) << 4) | (((k >> 4) & 3) << 2);
}
// register-transpose permutation: hw-k -> storage-s after 4x permlane32_swap
// s = {k5, k3, k4, k2, k1, k0}
__device__ __forceinline__ int rperm(int k) {
    return (k & 32) | (((k >> 3) & 1) << 4) | (((k >> 4) & 1) << 3) | (k & 7);
}

// ---------------- prologue: pack 36 A-fragments into d_ws ----------------
__global__ void pack_weights(const float* __restrict__ ws0, const float* __restrict__ ws1,
                             const float* __restrict__ ws2, const float* __restrict__ wc0,
                             const float* __restrict__ wc1, const float* __restrict__ wc2,
                             const float* __restrict__ wc3, uint4* __restrict__ wpack) {
    int idx = blockIdx.x * blockDim.x + threadIdx.x;
    if (idx >= NFRAGS * 64) return;
    int F = idx >> 6, cl = idx & 63, cm = cl & 15, cq = cl >> 4;
    const float* w; int IN, OUT, mt, ks, pm;
    if (F < 4)       { w = ws0; IN = 3;  OUT = 64; mt = F;            ks = 0;          pm = 0; }
    else if (F < 12) { w = ws1; IN = 64; OUT = 64; mt = (F-4) >> 1;   ks = (F-4) & 1;  pm = 2; }
    else if (F < 14) { w = ws2; IN = 64; OUT = 16; mt = 0;            ks = F - 12;     pm = 2; }
    else if (F < 18) { w = wc0; IN = 18; OUT = 64; mt = F - 14;       ks = 0;          pm = 0; }
    else if (F < 26) { w = wc1; IN = 64; OUT = 64; mt = (F-18) >> 1;  ks = (F-18) & 1; pm = 2; }
    else if (F < 34) { w = wc2; IN = 64; OUT = 64; mt = (F-26) >> 1;  ks = (F-26) & 1; pm = 2; }
    else             { w = wc3; IN = 64; OUT = 3;  mt = 0;            ks = F - 34;     pm = 2; }
    const int fo = mt * 16 + cm;
    uint32_t pk[4];
    for (int jj = 0; jj < 4; ++jj) {
        uint32_t h[2];
        for (int bb = 0; bb < 2; ++bb) {
            int kg = ks * 32 + cq * 8 + jj * 2 + bb;      // hw k position
            int kr = (pm == 2) ? sperm(rperm(kg)) : kg;   // source feature index
            float v = 0.f;
            if (fo < OUT && kr < IN) v = w[kr * OUT + fo];
            h[bb] = f2bf_rne(v);
        }
        pk[jj] = h[0] | (h[1] << 16);
    }
    wpack[F * 64 + cl] = make_uint4(pk[0], pk[1], pk[2], pk[3]);
}

// asm weight-fragment load: volatile so the compiler CANNOT sink it to the
// use site (R1's source-level prefetch was sunk; VGPR tell stayed 64).
// base is a uniform pointer (SGPR pair), voff = lane*16, offset imm <= 3072.
#define GLD(dst, base, off) \
    asm volatile("global_load_dwordx4 %0, %1, %2 offset:" #off \
                 : "=v"(dst) : "v"(voff), "s"(base))
// counted vmcnt wait (catalog T4) + rule-#18 fence so MFMAs can't hoist
// above the wait.
#define VMW(N) do { asm volatile("s_waitcnt vmcnt(" #N ")" ::: "memory"); \
                    __builtin_amdgcn_sched_barrier(0); } while (0)

// ---------------- main kernel ----------------
// R9 = best-known structure (T=4, NW=4, paired-tile 16KB LDS, setprio on
// 64->64 MFMA clusters, granule-0-only staging + masked L0/L3 reads +
// granule-2-only zeroing) + INLINE-ASM WEIGHT PIPELINE: each layer's 
// fragments are issued via volatile global_load_dwordx4 one layer early and
// drained with counted s_waitcnt vmcnt(N) (never 0 mid-kernel), so the 7
// layer-head load stalls (~200cy each) overlap the previous layer's MFMAs.
// Issue/wait schedule (out = outstanding): LA4,LB8 -> w(8) L0 -> LC2,w(2) L1
// -> LD4,w(4) L2 -> LE8+LFa4,w(12) L3 -> LFb4+LG2,w(10) L4 -> w(2) L5 ->
// w(0) L6. All compiler-issued loads (x) drain before the first asm load.
// HISTORY (do not revisit): source-level prefetch (R1: compiler sank it);
// LDS-weights+persistent (R3: 51.5); MFMA pair-bursts (R6: re-serialized);
// NW=8 (R7: 47.5, churn not the limiter); T=6 (R8: spilled, FETCH/WRITE
// rose); launch_bounds(,8) (32-reg cap, 1.2GB spill).
__global__ __launch_bounds__(BS, 4) void nerf_main(const float* __restrict__ xin,
                                                   const uint4* __restrict__ wpack,
                                                   float* __restrict__ outp, int n) {
    __shared__ __align__(16) char smem[NW * T * 1024];   // 16 KB
    const int tid = threadIdx.x, wv = tid >> 6, lane = tid & 63;
    const int p = lane & 15, q = lane >> 4;
    const int sw = p & 7;
    char* actw = smem + wv * (T * 1024);
    const int base = blockIdx.x * PTS_BLK + wv * (T * 16);

    // paired-tile swizzled address: tile t granule g (g in 0..3)
    auto aaddr = [&](int t, int g) -> char* {
        return actw + (t >> 1) * 2048 + p * 128 + (((g ^ ((t & 1) << 2)) ^ sw) << 4);
    };
    const f32x4 z4 = {0.f, 0.f, 0.f, 0.f};

    // D (4 m-tiles) -> pack+relu -> 4x v_permlane32_swap -> next layer's B frags.
    auto xpose = [&](const f32x4* d, bf16x8& b0, bf16x8& b1) {
        uint32_t X0 = pk2r(d[0][0], d[0][1]), X1 = pk2r(d[0][2], d[0][3]);
        uint32_t X2 = pk2r(d[1][0], d[1][1]), X3 = pk2r(d[1][2], d[1][3]);
        uint32_t X4 = pk2r(d[2][0], d[2][1]), X5 = pk2r(d[2][2], d[2][3]);
        uint32_t X6 = pk2r(d[3][0], d[3][1]), X7 = pk2r(d[3][2], d[3][3]);
        asm("v_permlane32_swap_b32 %0, %1" : "+v"(X0), "+v"(X4));
        asm("v_permlane32_swap_b32 %0, %1" : "+v"(X1), "+v"(X5));
        asm("v_permlane32_swap_b32 %0, %1" : "+v"(X2), "+v"(X6));
        asm("v_permlane32_swap_b32 %0, %1" : "+v"(X3), "+v"(X7));
        uint4 u0 = make_uint4(X0, X1, X2, X3), u1 = make_uint4(X4, X5, X6, X7);
        b0 = *(bf16x8*)&u0; b1 = *(bf16x8*)&u1;
    };

    // ---- staging FIRST (x loads + their waitcnt fully precede asm loads):
    // lane (p,q) stages tile q, point base+q*16+p. Only granule 0 written.
    float vv0 = 0.f, vv1 = 0.f, vv2 = 0.f;
    {
        float x0 = 0.f, x1 = 0.f, x2 = 0.f;
        const int pi = base + q * 16 + p;
        if (pi < n) {
            const float2* xp = (const float2*)(xin + (size_t)pi * 6);
            float2 a = xp[0], b = xp[1], c = xp[2];
            x0 = a.x; x1 = a.y; x2 = b.x; vv0 = b.y; vv1 = c.x; vv2 = c.y;
        }
        *(uint4*)aaddr(q, 0) = make_uint4(pk2(x0, x1), pk2(x2, 0.f), 0u, 0u);
    }

    bf16x8 c0[T], c1[T];   // live activation fragments (register path)

    // K=32 LDS-fed layer (L0: ws0 qmax=1, L3: wc0 qmax=3) — per-tile xpose
    auto layerK32 = [&](const bf16x8 (&W)[4], int qmax) {
#pragma unroll
        for (int t = 0; t < T; ++t) {
            bf16x8 b = 0;
            if (q < qmax) b = *(const bf16x8*)aaddr(t, q);
            f32x4 d[4];
            d[0] = __builtin_amdgcn_mfma_f32_16x16x32_bf16(W[0], b, z4, 0, 0, 0);
            d[1] = __builtin_amdgcn_mfma_f32_16x16x32_bf16(W[1], b, z4, 0, 0, 0);
            d[2] = __builtin_amdgcn_mfma_f32_16x16x32_bf16(W[2], b, z4, 0, 0, 0);
            d[3] = __builtin_amdgcn_mfma_f32_16x16x32_bf16(W[3], b, z4, 0, 0, 0);
            xpose(d, c0[t], c1[t]);
        }
    };

    // 64->64 register-fed layer — per-tile xpose, MFMA cluster under setprio
    auto layer64 = [&](const bf16x8 (&W)[8]) {
#pragma unroll
        for (int t = 0; t < T; ++t) {
            f32x4 d[4];
            __builtin_amdgcn_s_setprio(1);
#pragma unroll
            for (int mt = 0; mt < 4; ++mt) {
                f32x4 acc = __builtin_amdgcn_mfma_f32_16x16x32_bf16(W[mt*2],   c0[t], z4,  0, 0, 0);
                d[mt]     = __builtin_amdgcn_mfma_f32_16x16x32_bf16(W[mt*2+1], c1[t], acc, 0, 0, 0);
            }
            __builtin_amdgcn_s_setprio(0);
            xpose(d, c0[t], c1[t]);
        }
    };

    // ---- weight pipeline: bases (uniform SGPR pairs), voff (lane*16) ----
    const uint32_t voff = (uint32_t)lane * 16u;
    const uint4 *b0p = wpack,            *b4p = wpack + 4*64,  *b8p = wpack + 8*64;
    const uint4 *b12p = wpack + 12*64,   *b14p = wpack + 14*64;
    const uint4 *b18p = wpack + 18*64,   *b22p = wpack + 22*64;
    const uint4 *b26p = wpack + 26*64,   *b30p = wpack + 30*64, *b34p = wpack + 34*64;

    bf16x8 LA[4], LB[8];
    GLD(LA[0], b0p, 0); GLD(LA[1], b0p, 1024); GLD(LA[2], b0p, 2048); GLD(LA[3], b0p, 3072);
    GLD(LB[0], b4p, 0); GLD(LB[1], b4p, 1024); GLD(LB[2], b4p, 2048); GLD(LB[3], b4p, 3072);
    GLD(LB[4], b8p, 0); GLD(LB[5], b8p, 1024); GLD(LB[6], b8p, 2048); GLD(LB[7], b8p, 3072);

    // ---- L0: sigma net 3->64 ----
    VMW(8);                                   // LA ready (LB in flight)
    layerK32(LA, 1);
    bf16x8 LC[2];
    GLD(LC[0], b12p, 0); GLD(LC[1], b12p, 1024);

    // ---- L1: sigma net 64->64 ----
    VMW(2);                                   // LB ready (LC in flight)
    layer64(LB);
    bf16x8 LD[4];
    GLD(LD[0], b14p, 0); GLD(LD[1], b14p, 1024); GLD(LD[2], b14p, 2048); GLD(LD[3], b14p, 3072);

    // ---- L2: ws2 64->16: sigma + color-input assembly (LDS) ----
    VMW(4);                                   // LC ready (LD in flight)
    float sig[T];
    {
#pragma unroll
        for (int t = 0; t < T; ++t) {
            f32x4 acc = __builtin_amdgcn_mfma_f32_16x16x32_bf16(LC[0], c0[t], z4,  0, 0, 0);
            f32x4 d   = __builtin_amdgcn_mfma_f32_16x16x32_bf16(LC[1], c1[t], acc, 0, 0, 0);
            const float sx = d[0];                       // feat0 valid on q==0 lanes
            sig[t] = fmaxf(sx, 0.f) + __logf(1.f + __expf(-fabsf(sx)));
            // granules 0/1 fully overwritten below; granule 2 zeroed (k=18..23
            // dead); granule 3 never read (L3 uses q<3).
            if (q == 2) *(uint4*)aaddr(t, 2) = make_uint4(0u, 0u, 0u, 0u);
            if (q == t) {   // views of point p, tile t live on lane (p, t)
                *(uint32_t*)(aaddr(t, 0) + 0) = pk2(vv0, vv1);
                *(uint16_t*)(aaddr(t, 0) + 4) = bfu(vv2);
            }
            // geo feats f=4q+r (f>=1) -> color k=f+2
            if (q == 0) {
                *(uint16_t*)(aaddr(t, 0) + 6) = bfu(d[1]);
                *(uint32_t*)(aaddr(t, 0) + 8) = pk2(d[2], d[3]);
            } else if (q == 1) {
                *(uint32_t*)(aaddr(t, 0) + 12) = pk2(d[0], d[1]);
                *(uint32_t*)(aaddr(t, 1) + 0)  = pk2(d[2], d[3]);
            } else if (q == 2) {
                *(uint32_t*)(aaddr(t, 1) + 4) = pk2(d[0], d[1]);
                *(uint32_t*)(aaddr(t, 1) + 8) = pk2(d[2], d[3]);
            } else {
                *(uint32_t*)(aaddr(t, 1) + 12) = pk2(d[0], d[1]);
                *(uint32_t*)(aaddr(t, 2) + 0)  = pk2(d[2], d[3]);
            }
        }
    }
    bf16x8 LE[8], LF[8];
    GLD(LE[0], b18p, 0); GLD(LE[1], b18p, 1024); GLD(LE[2], b18p, 2048); GLD(LE[3], b18p, 3072);
    GLD(LE[4], b22p, 0); GLD(LE[5], b22p, 1024); GLD(LE[6], b22p, 2048); GLD(LE[7], b22p, 3072);
    GLD(LF[0], b26p, 0); GLD(LF[1], b26p, 1024); GLD(LF[2], b26p, 2048); GLD(LF[3], b26p, 3072);

    // ---- L3: wc0 18->64 ----
    VMW(12);                                  // LD ready (LE + LFa in flight)
    layerK32(LD, 3);
    GLD(LF[4], b30p, 0); GLD(LF[5], b30p, 1024); GLD(LF[6], b30p, 2048); GLD(LF[7], b30p, 3072);
    bf16x8 LG[2];
    GLD(LG[0], b34p, 0); GLD(LG[1], b34p, 1024);

    // ---- L4: wc1 64->64 ----
    VMW(10);                                  // LE ready (LFa+LFb+LG in flight)
    layer64(LE);

    // ---- L5: wc2 64->64 ----
    VMW(2);                                   // LF ready (LG in flight)
    layer64(LF);

    // ---- L6: wc3 64->3 + output ----
    VMW(0);                                   // LG ready
    {
#pragma unroll
        for (int t = 0; t < T; ++t) {
            f32x4 acc = __builtin_amdgcn_mfma_f32_16x16x32_bf16(LG[0], c0[t], z4,  0, 0, 0);
            f32x4 d   = __builtin_amdgcn_mfma_f32_16x16x32_bf16(LG[1], c1[t], acc, 0, 0, 0);
            if (q == 0) {
                const int pt = base + t * 16 + p;
                if (pt < n)
                    *(float4*)(outp + (size_t)pt * 4) = make_float4(d[0], d[1], d[2], sig[t]);
            }
        }
    }
}

extern "C" void kernel_launch(void* const* d_in, const int* in_sizes, int n_in,
                              void* d_out, int out_size, void* d_ws, size_t ws_size,
                              hipStream_t stream) {
    const float* x   = (const float*)d_in[0];
    const float* ws0 = (const float*)d_in[1];
    const float* ws1 = (const float*)d_in[2];
    const float* ws2 = (const float*)d_in[3];
    const float* wc0 = (const float*)d_in[4];
    const float* wc1 = (const float*)d_in[5];
    const float* wc2 = (const float*)d_in[6];
    const float* wc3 = (const float*)d_in[7];
    float* out = (float*)d_out;
    uint4* wpack = (uint4*)d_ws;

    const int n = in_sizes[0] / 6;
    pack_weights<<<(NFRAGS * 64 + 255) / 256, 256, 0, stream>>>(ws0, ws1, ws2, wc0, wc1, wc2, wc3, wpack);
    const int grid = (n + PTS_BLK - 1) / PTS_BLK;
    nerf_main<<<grid, BS, 0, stream>>>(x, wpack, out, n);
}